// Round 2
// baseline (122.862 us; speedup 1.0000x reference)
//
#include <hip/hip_runtime.h>
#include <hip/hip_bf16.h>
#include <stdint.h>

typedef __bf16 bf16x8 __attribute__((ext_vector_type(8)));
typedef float  f32x4  __attribute__((ext_vector_type(4)));

#define N_EMBED   2048
#define N_EXP     64
#define KCHUNK    64
#define NKC       (N_EMBED / KCHUNK)   // 32

// ---------------------------------------------------------------------------
// Prelude: W [64][2048] fp32 -> fragment-linear bf16 hi/lo image in ws.
// Folds the 0.5 = (alpha-1)/temperature scale into W.
// Record for (kc,t,s): 2048 bytes at ((kc*4+t)*2+s)*2048.
//   [0,1024):    hi fragment — lane l's 16B at lane*16 holds
//                W[e=16t+(l&15)][kc*64 + s*32 + (l>>4)*8 .. +8]
//   [1024,2048): lo fragment, same mapping.
// Each wave B-fragment load is one contiguous, coalesced 1 KB line (L2-hit).
// ---------------------------------------------------------------------------
__global__ __launch_bounds__(256) void convert_w_kernel(
        const float* __restrict__ W, uint8_t* __restrict__ img) {
    int tid  = blockIdx.x * 256 + threadIdx.x;   // 16384 threads total
    int f    = tid >> 6;                          // fragment record 0..255
    int lane = tid & 63;
    int kc = f >> 3, t = (f >> 1) & 3, s = f & 1;
    int e  = t * 16 + (lane & 15);
    int d  = kc * 64 + s * 32 + (lane >> 4) * 8;
    const float* src = W + e * N_EMBED + d;
    float4 f0 = *(const float4*)(src);
    float4 f1 = *(const float4*)(src + 4);
    float v[8] = {f0.x, f0.y, f0.z, f0.w, f1.x, f1.y, f1.z, f1.w};
    union { __bf16 h[8]; uint4 u; } hi, lo;
#pragma unroll
    for (int j = 0; j < 8; ++j) {
        float sc = 0.5f * v[j];
        __bf16 h = (__bf16)sc;
        hi.h[j] = h;
        lo.h[j] = (__bf16)(sc - (float)h);
    }
    uint8_t* base = img + (size_t)f * 2048 + lane * 16;
    *(uint4*)(base)        = hi.u;
    *(uint4*)(base + 1024) = lo.u;
}

// ---------------------------------------------------------------------------
// Main fused kernel: barrier-free streaming GEMM (split-bf16 MFMA) + entmax.
// 4 independent waves/block, 16 token-rows per wave, all 64 experts per wave.
// No LDS, no __syncthreads: A (x, HBM) double-buffered in registers, B (W)
// fragments read directly from the L2-resident fragment image.
// ---------------------------------------------------------------------------
__device__ inline void split8(const float4& p, const float4& q,
                              bf16x8& h8, bf16x8& l8) {
    float v[8] = {p.x, p.y, p.z, p.w, q.x, q.y, q.z, q.w};
#pragma unroll
    for (int j = 0; j < 8; ++j) {
        __bf16 h = (__bf16)v[j];
        h8[j] = h;
        l8[j] = (__bf16)(v[j] - (float)h);
    }
}

__device__ inline void kstep(const uint8_t* fb, float4 c0, float4 c1,
                             float4 c2, float4 c3, f32x4 acc[4]) {
    // B fragments: hi at fb + (2t+s)*2048, lo at +1024 (fb includes lane*16)
    bf16x8 bh[4][2], bl[4][2];
#pragma unroll
    for (int t = 0; t < 4; ++t)
#pragma unroll
        for (int s = 0; s < 2; ++s) {
            bh[t][s] = *(const bf16x8*)(fb + (2 * t + s) * 2048);
            bl[t][s] = *(const bf16x8*)(fb + (2 * t + s) * 2048 + 1024);
        }
    bf16x8 ah0, al0, ah1, al1;
    split8(c0, c1, ah0, al0);
    split8(c2, c3, ah1, al1);
#pragma unroll
    for (int s = 0; s < 2; ++s) {
        bf16x8 ah = s ? ah1 : ah0;
        bf16x8 al = s ? al1 : al0;
#pragma unroll
        for (int t = 0; t < 4; ++t) {
            acc[t] = __builtin_amdgcn_mfma_f32_16x16x32_bf16(ah, bh[t][s], acc[t], 0, 0, 0);
            acc[t] = __builtin_amdgcn_mfma_f32_16x16x32_bf16(al, bh[t][s], acc[t], 0, 0, 0);
            acc[t] = __builtin_amdgcn_mfma_f32_16x16x32_bf16(ah, bl[t][s], acc[t], 0, 0, 0);
        }
    }
}

__global__ __launch_bounds__(256) void router_kernel(
        const float* __restrict__ x, const uint8_t* __restrict__ img,
        const float* __restrict__ bias, float* __restrict__ out) {
    const int tid  = threadIdx.x;
    const int wave = tid >> 6;
    const int lane = tid & 63;
    const int l15  = lane & 15;
    const int l4   = lane >> 4;
    const int rowbase = blockIdx.x * 64 + wave * 16;
    const float* xrow = x + (size_t)(rowbase + l15) * N_EMBED + l4 * 8;
    const uint8_t* fbase = img + lane * 16;

    f32x4 acc[4];
#pragma unroll
    for (int t = 0; t < 4; ++t) acc[t] = (f32x4){0.f, 0.f, 0.f, 0.f};

    // A current (kc=0)
    float4 c0 = *(const float4*)(xrow);
    float4 c1 = *(const float4*)(xrow + 4);
    float4 c2 = *(const float4*)(xrow + 32);
    float4 c3 = *(const float4*)(xrow + 36);

#pragma unroll 1
    for (int kc = 0; kc < NKC - 1; ++kc) {
        // prefetch next A chunk (HBM) — stays in flight through this chunk's MFMAs
        const float* np = xrow + (kc + 1) * KCHUNK;
        float4 n0 = *(const float4*)(np);
        float4 n1 = *(const float4*)(np + 4);
        float4 n2 = *(const float4*)(np + 32);
        float4 n3 = *(const float4*)(np + 36);
        kstep(fbase + (size_t)kc * 16384, c0, c1, c2, c3, acc);
        c0 = n0; c1 = n1; c2 = n2; c3 = n3;
    }
    kstep(fbase + (size_t)(NKC - 1) * 16384, c0, c1, c2, c3, acc);

    // ---------------- entmax-1.5 epilogue ----------------
    // C layout: expert e = t*16 + l15, token row = rowbase + l4*4 + reg.
    float bv0 = 0.5f * bias[l15];
    float bv1 = 0.5f * bias[16 + l15];
    float bv2 = 0.5f * bias[32 + l15];
    float bv3 = 0.5f * bias[48 + l15];

#pragma unroll
    for (int r = 0; r < 4; ++r) {
        float v0 = acc[0][r] + bv0;
        float v1 = acc[1][r] + bv1;
        float v2 = acc[2][r] + bv2;
        float v3 = acc[3][r] + bv3;

        float m = fmaxf(fmaxf(v0, v1), fmaxf(v2, v3));
        m = fmaxf(m, __shfl_xor(m, 1, 64));
        m = fmaxf(m, __shfl_xor(m, 2, 64));
        m = fmaxf(m, __shfl_xor(m, 4, 64));
        m = fmaxf(m, __shfl_xor(m, 8, 64));

        float tau_lo = m - 1.0f;
        float tau_hi = m - 0.000244140625f;   // (1/64)^(1/(alpha-1)) = (1/64)^2
        float dm = tau_hi - tau_lo;

        float d0 = fmaxf(v0 - tau_lo, 0.f), d1 = fmaxf(v1 - tau_lo, 0.f);
        float d2 = fmaxf(v2 - tau_lo, 0.f), d3 = fmaxf(v3 - tau_lo, 0.f);
        float s0 = d0 * d0; s0 = fmaf(d1, d1, s0); s0 = fmaf(d2, d2, s0); s0 = fmaf(d3, d3, s0);
        s0 += __shfl_xor(s0, 1, 64);
        s0 += __shfl_xor(s0, 2, 64);
        s0 += __shfl_xor(s0, 4, 64);
        s0 += __shfl_xor(s0, 8, 64);
        const float f_lo = s0 - 1.0f;   // fixed for all iterations (as in reference)

        float tau_m = tau_lo, fsum = 1.0f;
#pragma unroll 1
        for (int it = 0; it < 25; ++it) {
            dm *= 0.5f;
            tau_m = tau_lo + dm;
            float e0 = fmaxf(v0 - tau_m, 0.f), e1 = fmaxf(v1 - tau_m, 0.f);
            float e2 = fmaxf(v2 - tau_m, 0.f), e3 = fmaxf(v3 - tau_m, 0.f);
            float s = e0 * e0; s = fmaf(e1, e1, s); s = fmaf(e2, e2, s); s = fmaf(e3, e3, s);
            s += __shfl_xor(s, 1, 64);
            s += __shfl_xor(s, 2, 64);
            s += __shfl_xor(s, 4, 64);
            s += __shfl_xor(s, 8, 64);
            if ((s - 1.0f) * f_lo >= 0.0f) tau_lo = tau_m;
            fsum = s;
        }
        // p at last midpoint, renormalized by its own sum (ensure_sum_one)
        float rinv = 1.0f / fsum;
        float p0 = fmaxf(v0 - tau_m, 0.f); p0 = p0 * p0 * rinv;
        float p1 = fmaxf(v1 - tau_m, 0.f); p1 = p1 * p1 * rinv;
        float p2 = fmaxf(v2 - tau_m, 0.f); p2 = p2 * p2 * rinv;
        float p3 = fmaxf(v3 - tau_m, 0.f); p3 = p3 * p3 * rinv;

        int trow = rowbase + l4 * 4 + r;
        float* op = out + (size_t)trow * N_EXP + l15;
        op[0]  = p0;
        op[16] = p1;
        op[32] = p2;
        op[48] = p3;
    }
}

// ---------------------------------------------------------------------------
extern "C" void kernel_launch(void* const* d_in, const int* in_sizes, int n_in,
                              void* d_out, int out_size, void* d_ws, size_t ws_size,
                              hipStream_t stream) {
    (void)n_in; (void)out_size; (void)ws_size;
    const float* x  = (const float*)d_in[0];   // [T, 2048]
    const float* W  = (const float*)d_in[1];   // [64, 2048]
    const float* b  = (const float*)d_in[2];   // [64]
    float* out      = (float*)d_out;           // [T, 64]
    uint8_t* wsimg  = (uint8_t*)d_ws;          // 512 KB W fragment image

    const int T = in_sizes[0] / N_EMBED;       // 32768

    convert_w_kernel<<<dim3(64), dim3(256), 0, stream>>>(W, wsimg);
    router_kernel<<<dim3(T / 64), dim3(256), 0, stream>>>(x, wsimg, b, out);
}

// Round 3
// 81.508 us; speedup vs baseline: 1.5074x; 1.5074x over previous
//
#include <hip/hip_runtime.h>
#include <hip/hip_bf16.h>
#include <stdint.h>

typedef __bf16 bf16x8 __attribute__((ext_vector_type(8)));
typedef float  f32x4  __attribute__((ext_vector_type(4)));

#define N_EMBED   2048
#define N_EXP     64
#define KCHUNK    64
#define NKC       (N_EMBED / KCHUNK)   // 32
#define TILEB     16384                // bytes per k-chunk image (hi 8KB + lo 8KB)

// ---------------------------------------------------------------------------
// Prelude: W [64][2048] fp32 -> pre-swizzled bf16 hi/lo image in ws.
// Folds the 0.5 = (alpha-1)/temperature scale into W.
// Image: for kc in [0,32): at kc*16384:
//   [0,8192)    : hi tile, element (e,dd) at byte ((e*128 + dd*2) ^ ((e&7)<<4))
//   [8192,16384): lo tile, same layout
// ---------------------------------------------------------------------------
__global__ __launch_bounds__(256) void convert_w_kernel(
        const float* __restrict__ W, uint8_t* __restrict__ wsimg) {
    int tid = blockIdx.x * 256 + threadIdx.x;   // 16384 threads total
    int e   = tid >> 8;                          // expert 0..63
    int d0  = (tid & 255) * 8;                   // 8 consecutive d
    int kc  = d0 >> 6;
    int dd0 = d0 & 63;
    const float* src = W + e * N_EMBED + d0;
    float4 f0 = *(const float4*)(src);
    float4 f1 = *(const float4*)(src + 4);
    float v[8] = {f0.x, f0.y, f0.z, f0.w, f1.x, f1.y, f1.z, f1.w};
    union { __bf16 h[8]; uint4 u; } hi, lo;
#pragma unroll
    for (int j = 0; j < 8; ++j) {
        float s = 0.5f * v[j];
        __bf16 h = (__bf16)s;
        hi.h[j] = h;
        lo.h[j] = (__bf16)(s - (float)h);
    }
    uint32_t off = (uint32_t)((e * 128 + dd0 * 2) ^ ((e & 7) << 4));
    uint8_t* base = wsimg + (size_t)kc * TILEB + off;
    *(uint4*)(base)        = hi.u;
    *(uint4*)(base + 8192) = lo.u;
}

// ---------------------------------------------------------------------------
// Main fused kernel: pipelined GEMM (split-bf16 MFMA) + entmax epilogue.
// Double-buffered LDS for W (counted vmcnt + raw s_barrier; NEVER vmcnt(0)
// in the hot loop), 2-chunk-deep register prefetch for A rows.
// ---------------------------------------------------------------------------
__device__ __forceinline__ void split8(const float4& p, const float4& q,
                                       bf16x8& h8, bf16x8& l8) {
    float v[8] = {p.x, p.y, p.z, p.w, q.x, q.y, q.z, q.w};
#pragma unroll
    for (int j = 0; j < 8; ++j) {
        __bf16 h = (__bf16)v[j];
        h8[j] = h;
        l8[j] = (__bf16)(v[j] - (float)h);
    }
}

__global__ __launch_bounds__(256, 2) void router_kernel(
        const float* __restrict__ x, const uint8_t* __restrict__ img,
        const float* __restrict__ bias, float* __restrict__ out) {
    __shared__ uint8_t lds[2 * TILEB];

    const int tid  = threadIdx.x;
    const int wave = tid >> 6;
    const int lane = tid & 63;
    const int l15  = lane & 15;
    const int l4   = lane >> 4;
    const int rowbase = blockIdx.x * 64 + wave * 16;
    const float* xrow = x + (size_t)(rowbase + l15) * N_EMBED + l4 * 8;

    // LDS byte offsets of B fragments (hi half): tile t, k-step s
    uint32_t boff[4][2];
#pragma unroll
    for (int t = 0; t < 4; ++t)
#pragma unroll
        for (int s = 0; s < 2; ++s)
            boff[t][s] = (uint32_t)(((16 * t + l15) * 128 + s * 64 + l4 * 16)
                                    ^ ((l15 & 7) << 4));

    f32x4 acc[4];
#pragma unroll
    for (int t = 0; t < 4; ++t) acc[t] = (f32x4){0.f, 0.f, 0.f, 0.f};

    auto STAGE = [&](int kc, int buf) {
        const uint8_t* gsrc = img + (size_t)kc * TILEB;
#pragma unroll
        for (int j = 0; j < 4; ++j) {
            __builtin_amdgcn_global_load_lds(
                (const __attribute__((address_space(1))) void*)(gsrc + j * 4096 + tid * 16),
                (__attribute__((address_space(3))) void*)(lds + (size_t)buf * TILEB + j * 4096 + tid * 16),
                16, 0, 0);
        }
    };
    auto LOADA = [&](int kc, float4& a0, float4& a1, float4& a2, float4& a3) {
        const float* ap = xrow + kc * KCHUNK;
        a0 = *(const float4*)(ap);
        a1 = *(const float4*)(ap + 4);
        a2 = *(const float4*)(ap + 32);
        a3 = *(const float4*)(ap + 36);
    };
    auto MFMAS = [&](int buf, const bf16x8& ah0, const bf16x8& al0,
                     const bf16x8& ah1, const bf16x8& al1) {
        const uint8_t* lb = lds + (size_t)buf * TILEB;
#pragma unroll
        for (int s = 0; s < 2; ++s) {
            bf16x8 ah = s ? ah1 : ah0;
            bf16x8 al = s ? al1 : al0;
#pragma unroll
            for (int t = 0; t < 4; ++t) {
                bf16x8 bh = *(const bf16x8*)(lb + boff[t][s]);
                bf16x8 bl = *(const bf16x8*)(lb + 8192 + boff[t][s]);
                acc[t] = __builtin_amdgcn_mfma_f32_16x16x32_bf16(ah, bh, acc[t], 0, 0, 0);
                acc[t] = __builtin_amdgcn_mfma_f32_16x16x32_bf16(al, bh, acc[t], 0, 0, 0);
                acc[t] = __builtin_amdgcn_mfma_f32_16x16x32_bf16(ah, bl, acc[t], 0, 0, 0);
            }
        }
    };

    // A register double-set: set0 holds even chunks, set1 odd chunks
    float4 A0, A1, A2, A3, B0, B1, B2, B3;

    // ---- prologue: stage W(0) -> buf0, load A(0), A(1) ----
    STAGE(0, 0);
    __builtin_amdgcn_sched_barrier(0);
    LOADA(0, A0, A1, A2, A3);
    LOADA(1, B0, B1, B2, B3);
    __builtin_amdgcn_sched_barrier(0);
    asm volatile("s_waitcnt vmcnt(8)" ::: "memory");   // W(0) staged; A loads in flight
    __builtin_amdgcn_s_barrier();
    __builtin_amdgcn_sched_barrier(0);

    // ---- hot loop: kc = 0..28 step 2, no guards ----
#pragma unroll 1
    for (int kc = 0; kc < NKC - 2; kc += 2) {
        // even half: read buf kc&1 (chunk kc), stage kc+1 -> other buf
        STAGE(kc + 1, (kc + 1) & 1);
        __builtin_amdgcn_sched_barrier(0);
        {
            bf16x8 ah0, al0, ah1, al1;
            split8(A0, A1, ah0, al0);       // waits A(kc); newer ops stay in flight
            split8(A2, A3, ah1, al1);
            LOADA(kc + 2, A0, A1, A2, A3);  // refill set0, 2 chunks ahead
            MFMAS(kc & 1, ah0, al0, ah1, al1);
        }
        asm volatile("s_waitcnt vmcnt(4) lgkmcnt(0)" ::: "memory"); // W(kc+1) landed; A(kc+2) in flight
        __builtin_amdgcn_s_barrier();
        __builtin_amdgcn_sched_barrier(0);

        // odd half: read other buf (chunk kc+1), stage kc+2
        STAGE(kc + 2, kc & 1);
        __builtin_amdgcn_sched_barrier(0);
        {
            bf16x8 ah0, al0, ah1, al1;
            split8(B0, B1, ah0, al0);
            split8(B2, B3, ah1, al1);
            LOADA(kc + 3, B0, B1, B2, B3);
            MFMAS((kc + 1) & 1, ah0, al0, ah1, al1);
        }
        asm volatile("s_waitcnt vmcnt(4) lgkmcnt(0)" ::: "memory");
        __builtin_amdgcn_s_barrier();
        __builtin_amdgcn_sched_barrier(0);
    }

    // ---- tail: kc = 30 (stage 31, no A load), kc = 31 ----
    STAGE(31, 1);
    __builtin_amdgcn_sched_barrier(0);
    {
        bf16x8 ah0, al0, ah1, al1;
        split8(A0, A1, ah0, al0);
        split8(A2, A3, ah1, al1);
        MFMAS(0, ah0, al0, ah1, al1);
    }
    asm volatile("s_waitcnt vmcnt(0) lgkmcnt(0)" ::: "memory");
    __builtin_amdgcn_s_barrier();
    __builtin_amdgcn_sched_barrier(0);
    {
        bf16x8 ah0, al0, ah1, al1;
        split8(B0, B1, ah0, al0);
        split8(B2, B3, ah1, al1);
        MFMAS(1, ah0, al0, ah1, al1);
    }

    // ---------------- entmax-1.5 epilogue ----------------
    // C layout: expert e = t*16 + l15, token row = rowbase + l4*4 + reg.
    float bv0 = 0.5f * bias[l15];
    float bv1 = 0.5f * bias[16 + l15];
    float bv2 = 0.5f * bias[32 + l15];
    float bv3 = 0.5f * bias[48 + l15];

#pragma unroll
    for (int r = 0; r < 4; ++r) {
        float v0 = acc[0][r] + bv0;
        float v1 = acc[1][r] + bv1;
        float v2 = acc[2][r] + bv2;
        float v3 = acc[3][r] + bv3;

        float m = fmaxf(fmaxf(v0, v1), fmaxf(v2, v3));
        m = fmaxf(m, __shfl_xor(m, 1, 64));
        m = fmaxf(m, __shfl_xor(m, 2, 64));
        m = fmaxf(m, __shfl_xor(m, 4, 64));
        m = fmaxf(m, __shfl_xor(m, 8, 64));

        float tau_lo = m - 1.0f;
        float tau_hi = m - 0.000244140625f;   // (1/64)^(1/(alpha-1)) = (1/64)^2
        float dm = tau_hi - tau_lo;

        float d0 = fmaxf(v0 - tau_lo, 0.f), d1 = fmaxf(v1 - tau_lo, 0.f);
        float d2 = fmaxf(v2 - tau_lo, 0.f), d3 = fmaxf(v3 - tau_lo, 0.f);
        float s0 = d0 * d0; s0 = fmaf(d1, d1, s0); s0 = fmaf(d2, d2, s0); s0 = fmaf(d3, d3, s0);
        s0 += __shfl_xor(s0, 1, 64);
        s0 += __shfl_xor(s0, 2, 64);
        s0 += __shfl_xor(s0, 4, 64);
        s0 += __shfl_xor(s0, 8, 64);
        const float f_lo = s0 - 1.0f;   // fixed for all iterations (as in reference)

        float tau_m = tau_lo, fsum = 1.0f;
#pragma unroll 1
        for (int it = 0; it < 25; ++it) {
            dm *= 0.5f;
            tau_m = tau_lo + dm;
            float e0 = fmaxf(v0 - tau_m, 0.f), e1 = fmaxf(v1 - tau_m, 0.f);
            float e2 = fmaxf(v2 - tau_m, 0.f), e3 = fmaxf(v3 - tau_m, 0.f);
            float s = e0 * e0; s = fmaf(e1, e1, s); s = fmaf(e2, e2, s); s = fmaf(e3, e3, s);
            s += __shfl_xor(s, 1, 64);
            s += __shfl_xor(s, 2, 64);
            s += __shfl_xor(s, 4, 64);
            s += __shfl_xor(s, 8, 64);
            if ((s - 1.0f) * f_lo >= 0.0f) tau_lo = tau_m;
            fsum = s;
        }
        // p at last midpoint, renormalized by its own sum (ensure_sum_one)
        float rinv = 1.0f / fsum;
        float p0 = fmaxf(v0 - tau_m, 0.f); p0 = p0 * p0 * rinv;
        float p1 = fmaxf(v1 - tau_m, 0.f); p1 = p1 * p1 * rinv;
        float p2 = fmaxf(v2 - tau_m, 0.f); p2 = p2 * p2 * rinv;
        float p3 = fmaxf(v3 - tau_m, 0.f); p3 = p3 * p3 * rinv;

        int trow = rowbase + l4 * 4 + r;
        float* op = out + (size_t)trow * N_EXP + l15;
        op[0]  = p0;
        op[16] = p1;
        op[32] = p2;
        op[48] = p3;
    }
}

// ---------------------------------------------------------------------------
extern "C" void kernel_launch(void* const* d_in, const int* in_sizes, int n_in,
                              void* d_out, int out_size, void* d_ws, size_t ws_size,
                              hipStream_t stream) {
    (void)n_in; (void)out_size; (void)ws_size;
    const float* x  = (const float*)d_in[0];   // [T, 2048]
    const float* W  = (const float*)d_in[1];   // [64, 2048]
    const float* b  = (const float*)d_in[2];   // [64]
    float* out      = (float*)d_out;           // [T, 64]
    uint8_t* wsimg  = (uint8_t*)d_ws;          // 512 KB W image

    const int T = in_sizes[0] / N_EMBED;       // 32768

    convert_w_kernel<<<dim3(64), dim3(256), 0, stream>>>(W, wsimg);
    router_kernel<<<dim3(T / 64), dim3(256), 0, stream>>>(x, wsimg, b, out);
}

// Round 4
// 72.296 us; speedup vs baseline: 1.6994x; 1.1274x over previous
//
#include <hip/hip_runtime.h>
#include <hip/hip_bf16.h>
#include <stdint.h>

typedef __bf16 bf16x8 __attribute__((ext_vector_type(8)));
typedef float  f32x4  __attribute__((ext_vector_type(4)));

#define N_EMBED   2048
#define N_EXP     64
#define KCHUNK    64
#define NKC       (N_EMBED / KCHUNK)   // 32
#define GCH       16                   // chunks per K-group (K-split 2)
#define TILEB     16384                // bytes per k-chunk image (hi 8KB + lo 8KB)
#define LGT_STRIDE 68                  // floats, padded row stride for logit LDS
#define LGT_FLOATS (64 * LGT_STRIDE)   // 4352 floats = 17408 B per region

// ---------------------------------------------------------------------------
// Prelude: W [64][2048] fp32 -> pre-swizzled bf16 hi/lo image in ws.
// Folds the 0.5 = (alpha-1)/temperature scale into W.
// Image: for kc in [0,32): at kc*16384:
//   [0,8192)    : hi tile, element (e,dd) at byte ((e*128 + dd*2) ^ ((e&7)<<4))
//   [8192,16384): lo tile, same layout
// ---------------------------------------------------------------------------
__global__ __launch_bounds__(256) void convert_w_kernel(
        const float* __restrict__ W, uint8_t* __restrict__ wsimg) {
    int tid = blockIdx.x * 256 + threadIdx.x;   // 16384 threads total
    int e   = tid >> 8;                          // expert 0..63
    int d0  = (tid & 255) * 8;                   // 8 consecutive d
    int kc  = d0 >> 6;
    int dd0 = d0 & 63;
    const float* src = W + e * N_EMBED + d0;
    float4 f0 = *(const float4*)(src);
    float4 f1 = *(const float4*)(src + 4);
    float v[8] = {f0.x, f0.y, f0.z, f0.w, f1.x, f1.y, f1.z, f1.w};
    union { __bf16 h[8]; uint4 u; } hi, lo;
#pragma unroll
    for (int j = 0; j < 8; ++j) {
        float s = 0.5f * v[j];
        __bf16 h = (__bf16)s;
        hi.h[j] = h;
        lo.h[j] = (__bf16)(s - (float)h);
    }
    uint32_t off = (uint32_t)((e * 128 + dd0 * 2) ^ ((e & 7) << 4));
    uint8_t* base = wsimg + (size_t)kc * TILEB + off;
    *(uint4*)(base)        = hi.u;
    *(uint4*)(base + 8192) = lo.u;
}

// ---------------------------------------------------------------------------
// Main fused kernel, K-split 2 for occupancy:
//   512 threads = 8 waves = 2 K-groups x 4 row-quads.
//   Group g: K-chunks [16g, 16g+16), private LDS double-buffer (2 x 16 KB).
//   Pipeline per iteration: STAGE(next W) / split A / prefetch A+2 / MFMA,
//   counted vmcnt (never 0 in hot loop) + raw s_barrier.
//   Epilogue: partial accs combined via LDS, entmax on all 8 waves.
// ---------------------------------------------------------------------------
__device__ __forceinline__ void split8(const float4& p, const float4& q,
                                       bf16x8& h8, bf16x8& l8) {
    float v[8] = {p.x, p.y, p.z, p.w, q.x, q.y, q.z, q.w};
#pragma unroll
    for (int j = 0; j < 8; ++j) {
        __bf16 h = (__bf16)v[j];
        h8[j] = h;
        l8[j] = (__bf16)(v[j] - (float)h);
    }
}

__global__ __launch_bounds__(512, 4) void router_kernel(
        const float* __restrict__ x, const uint8_t* __restrict__ img,
        const float* __restrict__ bias, float* __restrict__ out) {
    __shared__ uint8_t lds[65536];

    const int tid  = threadIdx.x;
    const int wave = tid >> 6;
    const int lane = tid & 63;
    const int l15  = lane & 15;
    const int l4   = lane >> 4;
    const int g    = wave >> 2;        // K-group
    const int q    = wave & 3;         // row quad
    const int rowbase = blockIdx.x * 64;
    // GEMM-phase rows: rowbase + q*16 + l15; K offset: group g
    const float* xrow = x + (size_t)(rowbase + q * 16 + l15) * N_EMBED
                          + g * (GCH * KCHUNK) + l4 * 8;
    uint8_t* lbase = lds + g * 32768;

    // LDS byte offsets of B fragments (hi half): tile t, k-step s
    uint32_t boff[4][2];
#pragma unroll
    for (int t = 0; t < 4; ++t)
#pragma unroll
        for (int s = 0; s < 2; ++s)
            boff[t][s] = (uint32_t)(((16 * t + l15) * 128 + s * 64 + l4 * 16)
                                    ^ ((l15 & 7) << 4));

    f32x4 acc[4];
#pragma unroll
    for (int t = 0; t < 4; ++t) acc[t] = (f32x4){0.f, 0.f, 0.f, 0.f};

    // Staging: all 512 threads; thread-group tg stages chunk tg*16+i.
    const int tg  = tid >> 8;
    const int t8  = tid & 255;
    auto STAGE = [&](int i, int buf) {
        const uint8_t* gsrc = img + (size_t)(tg * GCH + i) * TILEB;
        uint8_t* dst = lds + tg * 32768 + buf * TILEB;
#pragma unroll
        for (int j = 0; j < 4; ++j) {
            __builtin_amdgcn_global_load_lds(
                (const __attribute__((address_space(1))) void*)(gsrc + j * 4096 + t8 * 16),
                (__attribute__((address_space(3))) void*)(dst + j * 4096 + t8 * 16),
                16, 0, 0);
        }
    };
    auto LOADA = [&](int i, float4& a0, float4& a1, float4& a2, float4& a3) {
        const float* ap = xrow + i * KCHUNK;
        a0 = *(const float4*)(ap);
        a1 = *(const float4*)(ap + 4);
        a2 = *(const float4*)(ap + 32);
        a3 = *(const float4*)(ap + 36);
    };
    auto MFMAS = [&](int buf, const bf16x8& ah0, const bf16x8& al0,
                     const bf16x8& ah1, const bf16x8& al1) {
        const uint8_t* lb = lbase + (size_t)buf * TILEB;
#pragma unroll
        for (int s = 0; s < 2; ++s) {
            bf16x8 ah = s ? ah1 : ah0;
            bf16x8 al = s ? al1 : al0;
#pragma unroll
            for (int t = 0; t < 4; ++t) {
                bf16x8 bh = *(const bf16x8*)(lb + boff[t][s]);
                bf16x8 bl = *(const bf16x8*)(lb + 8192 + boff[t][s]);
                acc[t] = __builtin_amdgcn_mfma_f32_16x16x32_bf16(ah, bh, acc[t], 0, 0, 0);
                acc[t] = __builtin_amdgcn_mfma_f32_16x16x32_bf16(al, bh, acc[t], 0, 0, 0);
                acc[t] = __builtin_amdgcn_mfma_f32_16x16x32_bf16(ah, bl, acc[t], 0, 0, 0);
            }
        }
    };

    float4 A0, A1, A2, A3, B0, B1, B2, B3;

    // ---- prologue: stage local chunk 0, load A(0), A(1) ----
    STAGE(0, 0);
    __builtin_amdgcn_sched_barrier(0);
    LOADA(0, A0, A1, A2, A3);
    LOADA(1, B0, B1, B2, B3);
    __builtin_amdgcn_sched_barrier(0);
    asm volatile("s_waitcnt vmcnt(8)" ::: "memory");
    __builtin_amdgcn_s_barrier();
    __builtin_amdgcn_sched_barrier(0);

    // ---- hot loop: local chunks 0..13, step 2 ----
#pragma unroll 1
    for (int i = 0; i < GCH - 2; i += 2) {
        STAGE(i + 1, (i + 1) & 1);
        __builtin_amdgcn_sched_barrier(0);
        {
            bf16x8 ah0, al0, ah1, al1;
            split8(A0, A1, ah0, al0);
            split8(A2, A3, ah1, al1);
            LOADA(i + 2, A0, A1, A2, A3);
            MFMAS(i & 1, ah0, al0, ah1, al1);
        }
        asm volatile("s_waitcnt vmcnt(4) lgkmcnt(0)" ::: "memory");
        __builtin_amdgcn_s_barrier();
        __builtin_amdgcn_sched_barrier(0);

        STAGE(i + 2, i & 1);
        __builtin_amdgcn_sched_barrier(0);
        {
            bf16x8 ah0, al0, ah1, al1;
            split8(B0, B1, ah0, al0);
            split8(B2, B3, ah1, al1);
            LOADA(i + 3, B0, B1, B2, B3);
            MFMAS((i + 1) & 1, ah0, al0, ah1, al1);
        }
        asm volatile("s_waitcnt vmcnt(4) lgkmcnt(0)" ::: "memory");
        __builtin_amdgcn_s_barrier();
        __builtin_amdgcn_sched_barrier(0);
    }

    // ---- tail: local chunks 14, 15 ----
    STAGE(GCH - 1, 1);
    __builtin_amdgcn_sched_barrier(0);
    {
        bf16x8 ah0, al0, ah1, al1;
        split8(A0, A1, ah0, al0);
        split8(A2, A3, ah1, al1);
        MFMAS(0, ah0, al0, ah1, al1);
    }
    asm volatile("s_waitcnt vmcnt(0) lgkmcnt(0)" ::: "memory");
    __builtin_amdgcn_s_barrier();
    __builtin_amdgcn_sched_barrier(0);
    {
        bf16x8 ah0, al0, ah1, al1;
        split8(B0, B1, ah0, al0);
        split8(B2, B3, ah1, al1);
        MFMAS(1, ah0, al0, ah1, al1);
    }

    // ---- combine K-halves via LDS ----
    __syncthreads();   // all MFMA ds_reads done; safe to overwrite buffers
    {
        float* lgt = (float*)lds + g * LGT_FLOATS;
#pragma unroll
        for (int t = 0; t < 4; ++t)
#pragma unroll
            for (int r = 0; r < 4; ++r)
                lgt[(q * 16 + l4 * 4 + r) * LGT_STRIDE + t * 16 + l15] = acc[t][r];
    }
    __syncthreads();

    // ---------------- entmax-1.5 epilogue (all 8 waves; 2 rows-slices each) --
    const float* L0 = (const float*)lds;
    const float* L1 = L0 + LGT_FLOATS;
    float bv0 = 0.5f * bias[l15];
    float bv1 = 0.5f * bias[16 + l15];
    float bv2 = 0.5f * bias[32 + l15];
    float bv3 = 0.5f * bias[48 + l15];

#pragma unroll
    for (int rr = 0; rr < 2; ++rr) {
        int r = g * 2 + rr;
        int row_local = q * 16 + l4 * 4 + r;
        int base = row_local * LGT_STRIDE + l15;
        float v0 = L0[base]      + L1[base]      + bv0;
        float v1 = L0[base + 16] + L1[base + 16] + bv1;
        float v2 = L0[base + 32] + L1[base + 32] + bv2;
        float v3 = L0[base + 48] + L1[base + 48] + bv3;

        float m = fmaxf(fmaxf(v0, v1), fmaxf(v2, v3));
        m = fmaxf(m, __shfl_xor(m, 1, 64));
        m = fmaxf(m, __shfl_xor(m, 2, 64));
        m = fmaxf(m, __shfl_xor(m, 4, 64));
        m = fmaxf(m, __shfl_xor(m, 8, 64));

        float tau_lo = m - 1.0f;
        float tau_hi = m - 0.000244140625f;   // (1/64)^(1/(alpha-1)) = (1/64)^2
        float dm = tau_hi - tau_lo;

        float d0 = fmaxf(v0 - tau_lo, 0.f), d1 = fmaxf(v1 - tau_lo, 0.f);
        float d2 = fmaxf(v2 - tau_lo, 0.f), d3 = fmaxf(v3 - tau_lo, 0.f);
        float s0 = d0 * d0; s0 = fmaf(d1, d1, s0); s0 = fmaf(d2, d2, s0); s0 = fmaf(d3, d3, s0);
        s0 += __shfl_xor(s0, 1, 64);
        s0 += __shfl_xor(s0, 2, 64);
        s0 += __shfl_xor(s0, 4, 64);
        s0 += __shfl_xor(s0, 8, 64);
        const float f_lo = s0 - 1.0f;   // fixed for all iterations (as in reference)

        float tau_m = tau_lo, fsum = 1.0f;
#pragma unroll 1
        for (int it = 0; it < 25; ++it) {
            dm *= 0.5f;
            tau_m = tau_lo + dm;
            float e0 = fmaxf(v0 - tau_m, 0.f), e1 = fmaxf(v1 - tau_m, 0.f);
            float e2 = fmaxf(v2 - tau_m, 0.f), e3 = fmaxf(v3 - tau_m, 0.f);
            float s = e0 * e0; s = fmaf(e1, e1, s); s = fmaf(e2, e2, s); s = fmaf(e3, e3, s);
            s += __shfl_xor(s, 1, 64);
            s += __shfl_xor(s, 2, 64);
            s += __shfl_xor(s, 4, 64);
            s += __shfl_xor(s, 8, 64);
            if ((s - 1.0f) * f_lo >= 0.0f) tau_lo = tau_m;
            fsum = s;
        }
        // p at last midpoint, renormalized by its own sum (ensure_sum_one)
        float rinv = 1.0f / fsum;
        float p0 = fmaxf(v0 - tau_m, 0.f); p0 = p0 * p0 * rinv;
        float p1 = fmaxf(v1 - tau_m, 0.f); p1 = p1 * p1 * rinv;
        float p2 = fmaxf(v2 - tau_m, 0.f); p2 = p2 * p2 * rinv;
        float p3 = fmaxf(v3 - tau_m, 0.f); p3 = p3 * p3 * rinv;

        int trow = rowbase + row_local;
        float* op = out + (size_t)trow * N_EXP + l15;
        op[0]  = p0;
        op[16] = p1;
        op[32] = p2;
        op[48] = p3;
    }
}

// ---------------------------------------------------------------------------
extern "C" void kernel_launch(void* const* d_in, const int* in_sizes, int n_in,
                              void* d_out, int out_size, void* d_ws, size_t ws_size,
                              hipStream_t stream) {
    (void)n_in; (void)out_size; (void)ws_size;
    const float* x  = (const float*)d_in[0];   // [T, 2048]
    const float* W  = (const float*)d_in[1];   // [64, 2048]
    const float* b  = (const float*)d_in[2];   // [64]
    float* out      = (float*)d_out;           // [T, 64]
    uint8_t* wsimg  = (uint8_t*)d_ws;          // 512 KB W image

    const int T = in_sizes[0] / N_EMBED;       // 32768

    convert_w_kernel<<<dim3(64), dim3(256), 0, stream>>>(W, wsimg);
    router_kernel<<<dim3(T / 64), dim3(512), 0, stream>>>(x, wsimg, b, out);
}

// Round 5
// 63.201 us; speedup vs baseline: 1.9440x; 1.1439x over previous
//
#include <hip/hip_runtime.h>
#include <hip/hip_bf16.h>
#include <stdint.h>

typedef _Float16 half8 __attribute__((ext_vector_type(8)));
typedef float    f32x4 __attribute__((ext_vector_type(4)));

#define N_EMBED   2048
#define N_EXP     64
#define KCHUNK    64
#define NKC       (N_EMBED / KCHUNK)   // 32
#define GCH       16                   // chunks per K-group (K-split 2)
#define TILEB     8192                 // bytes per k-chunk fp16 image
#define LGT_STRIDE 68                  // floats, padded row stride for logit LDS
#define LGT_FLOATS (64 * LGT_STRIDE)   // 4352 floats = 17408 B per region

// ---------------------------------------------------------------------------
// Prelude: W [64][2048] fp32 -> pre-swizzled fp16 image in ws (256 KB).
// Folds the 0.5 = (alpha-1)/temperature scale into W.
// Chunk kc at kc*8192; element (e,dd) at byte ((e*128 + dd*2) ^ ((e&7)<<4)).
// ---------------------------------------------------------------------------
__global__ __launch_bounds__(256) void convert_w_kernel(
        const float* __restrict__ W, uint8_t* __restrict__ wsimg) {
    int tid = blockIdx.x * 256 + threadIdx.x;   // 16384 threads total
    int e   = tid >> 8;                          // expert 0..63
    int d0  = (tid & 255) * 8;                   // 8 consecutive d
    int kc  = d0 >> 6;
    int dd0 = d0 & 63;
    const float* src = W + e * N_EMBED + d0;
    float4 f0 = *(const float4*)(src);
    float4 f1 = *(const float4*)(src + 4);
    float v[8] = {f0.x, f0.y, f0.z, f0.w, f1.x, f1.y, f1.z, f1.w};
    union { _Float16 h[8]; uint4 u; } hv;
#pragma unroll
    for (int j = 0; j < 8; ++j) hv.h[j] = (_Float16)(0.5f * v[j]);
    uint32_t off = (uint32_t)((e * 128 + dd0 * 2) ^ ((e & 7) << 4));
    *(uint4*)(wsimg + (size_t)kc * TILEB + off) = hv.u;
}

// ---------------------------------------------------------------------------
// Main fused kernel, K-split 2, fp16 single-pass MFMA:
//   512 threads = 8 waves = 2 K-groups x 4 row-quads.
//   Group g: K-chunks [16g, 16g+16), private LDS double-buffer (2 x 8 KB).
//   Pipeline: STAGE(next W) / cvt A / prefetch A+2 / MFMA, counted vmcnt
//   (never 0 in hot loop) + raw s_barrier.
//   Epilogue: partials combined via LDS; row-per-8-lanes bisection (3 shfl).
// ---------------------------------------------------------------------------
__device__ __forceinline__ half8 cvt8(const float4& p, const float4& q) {
    half8 h;
    h[0] = (_Float16)p.x; h[1] = (_Float16)p.y;
    h[2] = (_Float16)p.z; h[3] = (_Float16)p.w;
    h[4] = (_Float16)q.x; h[5] = (_Float16)q.y;
    h[6] = (_Float16)q.z; h[7] = (_Float16)q.w;
    return h;
}

__global__ __launch_bounds__(512, 4) void router_kernel(
        const float* __restrict__ x, const uint8_t* __restrict__ img,
        const float* __restrict__ bias, float* __restrict__ out) {
    __shared__ uint8_t lds[2 * LGT_FLOATS * 4];   // 34816 B >= 32 KB staging

    const int tid  = threadIdx.x;
    const int wave = tid >> 6;
    const int lane = tid & 63;
    const int l15  = lane & 15;
    const int l4   = lane >> 4;
    const int g    = wave >> 2;        // K-group
    const int q    = wave & 3;         // row quad
    const int rowbase = blockIdx.x * 64;
    const float* xrow = x + (size_t)(rowbase + q * 16 + l15) * N_EMBED
                          + g * (GCH * KCHUNK) + l4 * 8;
    uint8_t* lbase = lds + g * 2 * TILEB;

    // LDS byte offsets of B fragments: tile t, k-step s
    uint32_t boff[4][2];
#pragma unroll
    for (int t = 0; t < 4; ++t)
#pragma unroll
        for (int s = 0; s < 2; ++s)
            boff[t][s] = (uint32_t)(((16 * t + l15) * 128 + s * 64 + l4 * 16)
                                    ^ ((l15 & 7) << 4));

    f32x4 acc[4];
#pragma unroll
    for (int t = 0; t < 4; ++t) acc[t] = (f32x4){0.f, 0.f, 0.f, 0.f};

    // Staging: thread-group tg (256 threads) stages its group's 8 KB chunk.
    const int tg  = tid >> 8;
    const int t8  = tid & 255;
    auto STAGE = [&](int i, int buf) {   // 2 global_load_lds per thread
        const uint8_t* gsrc = img + (size_t)(tg * GCH + i) * TILEB;
        uint8_t* dst = lds + tg * 2 * TILEB + buf * TILEB;
#pragma unroll
        for (int j = 0; j < 2; ++j) {
            __builtin_amdgcn_global_load_lds(
                (const __attribute__((address_space(1))) void*)(gsrc + j * 4096 + t8 * 16),
                (__attribute__((address_space(3))) void*)(dst + j * 4096 + t8 * 16),
                16, 0, 0);
        }
    };
    auto LOADA = [&](int i, float4& a0, float4& a1, float4& a2, float4& a3) {
        const float* ap = xrow + i * KCHUNK;
        a0 = *(const float4*)(ap);
        a1 = *(const float4*)(ap + 4);
        a2 = *(const float4*)(ap + 32);
        a3 = *(const float4*)(ap + 36);
    };
    auto MFMAS = [&](int buf, const half8& a0, const half8& a1) {
        const uint8_t* lb = lbase + (size_t)buf * TILEB;
#pragma unroll
        for (int s = 0; s < 2; ++s) {
            half8 ah = s ? a1 : a0;
#pragma unroll
            for (int t = 0; t < 4; ++t) {
                half8 bh = *(const half8*)(lb + boff[t][s]);
                acc[t] = __builtin_amdgcn_mfma_f32_16x16x32_f16(ah, bh, acc[t], 0, 0, 0);
            }
        }
    };

    float4 A0, A1, A2, A3, B0, B1, B2, B3;

    // ---- prologue: stage local chunk 0, load A(0), A(1) ----
    STAGE(0, 0);
    __builtin_amdgcn_sched_barrier(0);
    LOADA(0, A0, A1, A2, A3);
    LOADA(1, B0, B1, B2, B3);
    __builtin_amdgcn_sched_barrier(0);
    asm volatile("s_waitcnt vmcnt(8)" ::: "memory");   // W(0) landed; A in flight
    __builtin_amdgcn_s_barrier();
    __builtin_amdgcn_sched_barrier(0);

    // ---- hot loop: local chunks 0..13, step 2 ----
#pragma unroll 1
    for (int i = 0; i < GCH - 2; i += 2) {
        STAGE(i + 1, (i + 1) & 1);
        __builtin_amdgcn_sched_barrier(0);
        {
            half8 a0 = cvt8(A0, A1);
            half8 a1 = cvt8(A2, A3);
            LOADA(i + 2, A0, A1, A2, A3);
            MFMAS(i & 1, a0, a1);
        }
        asm volatile("s_waitcnt vmcnt(4) lgkmcnt(0)" ::: "memory"); // W(i+1) landed; A(i+2) in flight
        __builtin_amdgcn_s_barrier();
        __builtin_amdgcn_sched_barrier(0);

        STAGE(i + 2, i & 1);
        __builtin_amdgcn_sched_barrier(0);
        {
            half8 a0 = cvt8(B0, B1);
            half8 a1 = cvt8(B2, B3);
            LOADA(i + 3, B0, B1, B2, B3);
            MFMAS((i + 1) & 1, a0, a1);
        }
        asm volatile("s_waitcnt vmcnt(4) lgkmcnt(0)" ::: "memory");
        __builtin_amdgcn_s_barrier();
        __builtin_amdgcn_sched_barrier(0);
    }

    // ---- tail: local chunks 14, 15 ----
    STAGE(GCH - 1, 1);
    __builtin_amdgcn_sched_barrier(0);
    {
        half8 a0 = cvt8(A0, A1);
        half8 a1 = cvt8(A2, A3);
        MFMAS(0, a0, a1);
    }
    asm volatile("s_waitcnt vmcnt(0) lgkmcnt(0)" ::: "memory");
    __builtin_amdgcn_s_barrier();
    __builtin_amdgcn_sched_barrier(0);
    {
        half8 a0 = cvt8(B0, B1);
        half8 a1 = cvt8(B2, B3);
        MFMAS(1, a0, a1);
    }

    // ---- combine K-halves via LDS ----
    __syncthreads();   // all MFMA ds_reads done; safe to overwrite buffers
    {
        float* lgt = (float*)lds + g * LGT_FLOATS;
#pragma unroll
        for (int t = 0; t < 4; ++t)
#pragma unroll
            for (int r = 0; r < 4; ++r)
                lgt[(q * 16 + l4 * 4 + r) * LGT_STRIDE + t * 16 + l15] = acc[t][r];
    }
    __syncthreads();

    // ---------------- entmax-1.5 epilogue ----------------
    // 8 lanes per row, 8 experts per lane; reductions = 3 x shfl_xor {1,2,4}.
    const float* L0 = (const float*)lds;
    const float* L1 = L0 + LGT_FLOATS;
    const int row_local = wave * 8 + (lane >> 3);
    const int eb = (lane & 7) * 8;
    const int base = row_local * LGT_STRIDE + eb;

    float v[8];
    {
        float4 u0 = *(const float4*)(L0 + base);
        float4 u1 = *(const float4*)(L0 + base + 4);
        float4 w0 = *(const float4*)(L1 + base);
        float4 w1 = *(const float4*)(L1 + base + 4);
        float4 c0 = *(const float4*)(bias + eb);
        float4 c1 = *(const float4*)(bias + eb + 4);
        v[0] = u0.x + w0.x + 0.5f * c0.x;
        v[1] = u0.y + w0.y + 0.5f * c0.y;
        v[2] = u0.z + w0.z + 0.5f * c0.z;
        v[3] = u0.w + w0.w + 0.5f * c0.w;
        v[4] = u1.x + w1.x + 0.5f * c1.x;
        v[5] = u1.y + w1.y + 0.5f * c1.y;
        v[6] = u1.z + w1.z + 0.5f * c1.z;
        v[7] = u1.w + w1.w + 0.5f * c1.w;
    }

    float m = v[0];
#pragma unroll
    for (int j = 1; j < 8; ++j) m = fmaxf(m, v[j]);
    m = fmaxf(m, __shfl_xor(m, 1, 64));
    m = fmaxf(m, __shfl_xor(m, 2, 64));
    m = fmaxf(m, __shfl_xor(m, 4, 64));

    float tau_lo = m - 1.0f;
    float tau_hi = m - 0.000244140625f;   // (1/64)^(1/(alpha-1)) = (1/64)^2
    float dm = tau_hi - tau_lo;

    float s0 = 0.f;
#pragma unroll
    for (int j = 0; j < 8; ++j) {
        float d = fmaxf(v[j] - tau_lo, 0.f);
        s0 = fmaf(d, d, s0);
    }
    s0 += __shfl_xor(s0, 1, 64);
    s0 += __shfl_xor(s0, 2, 64);
    s0 += __shfl_xor(s0, 4, 64);
    const float f_lo = s0 - 1.0f;   // fixed for all iterations (as in reference)

    float tau_m = tau_lo, fsum = 1.0f;
#pragma unroll 1
    for (int it = 0; it < 25; ++it) {
        dm *= 0.5f;
        tau_m = tau_lo + dm;
        float s = 0.f;
#pragma unroll
        for (int j = 0; j < 8; ++j) {
            float d = fmaxf(v[j] - tau_m, 0.f);
            s = fmaf(d, d, s);
        }
        s += __shfl_xor(s, 1, 64);
        s += __shfl_xor(s, 2, 64);
        s += __shfl_xor(s, 4, 64);
        if ((s - 1.0f) * f_lo >= 0.0f) tau_lo = tau_m;
        fsum = s;
    }
    // p at last midpoint, renormalized by its own sum (ensure_sum_one)
    float rinv = 1.0f / fsum;
    float4 o0, o1;
    {
        float d;
        d = fmaxf(v[0] - tau_m, 0.f); o0.x = d * d * rinv;
        d = fmaxf(v[1] - tau_m, 0.f); o0.y = d * d * rinv;
        d = fmaxf(v[2] - tau_m, 0.f); o0.z = d * d * rinv;
        d = fmaxf(v[3] - tau_m, 0.f); o0.w = d * d * rinv;
        d = fmaxf(v[4] - tau_m, 0.f); o1.x = d * d * rinv;
        d = fmaxf(v[5] - tau_m, 0.f); o1.y = d * d * rinv;
        d = fmaxf(v[6] - tau_m, 0.f); o1.z = d * d * rinv;
        d = fmaxf(v[7] - tau_m, 0.f); o1.w = d * d * rinv;
    }
    float* op = out + (size_t)(rowbase + row_local) * N_EXP + eb;
    *(float4*)(op)     = o0;
    *(float4*)(op + 4) = o1;
}

// ---------------------------------------------------------------------------
extern "C" void kernel_launch(void* const* d_in, const int* in_sizes, int n_in,
                              void* d_out, int out_size, void* d_ws, size_t ws_size,
                              hipStream_t stream) {
    (void)n_in; (void)out_size; (void)ws_size;
    const float* x  = (const float*)d_in[0];   // [T, 2048]
    const float* W  = (const float*)d_in[1];   // [64, 2048]
    const float* b  = (const float*)d_in[2];   // [64]
    float* out      = (float*)d_out;           // [T, 64]
    uint8_t* wsimg  = (uint8_t*)d_ws;          // 256 KB W fp16 image

    const int T = in_sizes[0] / N_EMBED;       // 32768

    convert_w_kernel<<<dim3(64), dim3(256), 0, stream>>>(W, wsimg);
    router_kernel<<<dim3(T / 64), dim3(512), 0, stream>>>(x, wsimg, b, out);
}

// Round 6
// 60.788 us; speedup vs baseline: 2.0211x; 1.0397x over previous
//
#include <hip/hip_runtime.h>
#include <hip/hip_bf16.h>
#include <stdint.h>

typedef _Float16 half8 __attribute__((ext_vector_type(8)));
typedef float    f32x4 __attribute__((ext_vector_type(4)));

#define N_EMBED   2048
#define N_EXP     64
#define KCHUNK    64
#define NKC       (N_EMBED / KCHUNK)   // 32
#define GCH       16                   // chunks per K-group (K-split 2)
#define TILEB     8192                 // bytes per k-chunk fp16 image
#define LGT_STRIDE 68                  // floats, padded row stride for logit LDS
#define LGT_FLOATS (64 * LGT_STRIDE)   // 4352 floats = 17408 B per region

// ---------------------------------------------------------------------------
// Prelude: W [64][2048] fp32 -> pre-swizzled fp16 image in ws (256 KB).
// Folds the 0.5 = (alpha-1)/temperature scale into W.
// Chunk kc at kc*8192; element (e,dd) at byte ((e*128 + dd*2) ^ ((e&7)<<4)).
// ---------------------------------------------------------------------------
__global__ __launch_bounds__(256) void convert_w_kernel(
        const float* __restrict__ W, uint8_t* __restrict__ wsimg) {
    int tid = blockIdx.x * 256 + threadIdx.x;   // 16384 threads total
    int e   = tid >> 8;                          // expert 0..63
    int d0  = (tid & 255) * 8;                   // 8 consecutive d
    int kc  = d0 >> 6;
    int dd0 = d0 & 63;
    const float* src = W + e * N_EMBED + d0;
    float4 f0 = *(const float4*)(src);
    float4 f1 = *(const float4*)(src + 4);
    float v[8] = {f0.x, f0.y, f0.z, f0.w, f1.x, f1.y, f1.z, f1.w};
    union { _Float16 h[8]; uint4 u; } hv;
#pragma unroll
    for (int j = 0; j < 8; ++j) hv.h[j] = (_Float16)(0.5f * v[j]);
    uint32_t off = (uint32_t)((e * 128 + dd0 * 2) ^ ((e & 7) << 4));
    *(uint4*)(wsimg + (size_t)kc * TILEB + off) = hv.u;
}

// ---------------------------------------------------------------------------
// Main fused kernel, K-split 2, fp16 MFMA, DEEP W-pipeline:
//   512 threads = 8 waves = 2 K-groups x 4 row-quads.
//   W staging: ring-4 LDS (4 x 8 KB per group), stage-depth 3 — round i
//   issues STAGE(i+3) and waits for STAGE(i+1) (issued ~2 rounds earlier),
//   so gload_lds latency is covered by ~2 rounds of compute.
//   A: register double-set, depth 2. Counted vmcnt only; raw s_barrier.
// ---------------------------------------------------------------------------
__device__ __forceinline__ half8 cvt8(const float4& p, const float4& q) {
    half8 h;
    h[0] = (_Float16)p.x; h[1] = (_Float16)p.y;
    h[2] = (_Float16)p.z; h[3] = (_Float16)p.w;
    h[4] = (_Float16)q.x; h[5] = (_Float16)q.y;
    h[6] = (_Float16)q.z; h[7] = (_Float16)q.w;
    return h;
}

__global__ __launch_bounds__(512, 4) void router_kernel(
        const float* __restrict__ x, const uint8_t* __restrict__ img,
        const float* __restrict__ bias, float* __restrict__ out) {
    __shared__ uint8_t lds[65536];   // 2 groups x ring-4 x 8 KB; logits overlay

    const int tid  = threadIdx.x;
    const int wave = tid >> 6;
    const int lane = tid & 63;
    const int l15  = lane & 15;
    const int l4   = lane >> 4;
    const int g    = wave >> 2;        // K-group
    const int q    = wave & 3;         // row quad
    const int rowbase = blockIdx.x * 64;
    const float* xrow = x + (size_t)(rowbase + q * 16 + l15) * N_EMBED
                          + g * (GCH * KCHUNK) + l4 * 8;
    uint8_t* gring = lds + g * (4 * TILEB);

    // LDS byte offsets of B fragments: tile t, k-step s
    uint32_t boff[4][2];
#pragma unroll
    for (int t = 0; t < 4; ++t)
#pragma unroll
        for (int s = 0; s < 2; ++s)
            boff[t][s] = (uint32_t)(((16 * t + l15) * 128 + s * 64 + l4 * 16)
                                    ^ ((l15 & 7) << 4));

    f32x4 acc[4];
#pragma unroll
    for (int t = 0; t < 4; ++t) acc[t] = (f32x4){0.f, 0.f, 0.f, 0.f};

    // Staging: thread-group tg (256 threads) stages its group's 8 KB chunk
    // into ring slot (i & 3).
    const int tg  = tid >> 8;
    const int t8  = tid & 255;
    auto STAGE = [&](int i) {   // 2 global_load_lds per thread
        const uint8_t* gsrc = img + (size_t)(tg * GCH + i) * TILEB;
        uint8_t* dst = lds + tg * (4 * TILEB) + (i & 3) * TILEB;
#pragma unroll
        for (int j = 0; j < 2; ++j) {
            __builtin_amdgcn_global_load_lds(
                (const __attribute__((address_space(1))) void*)(gsrc + j * 4096 + t8 * 16),
                (__attribute__((address_space(3))) void*)(dst + j * 4096 + t8 * 16),
                16, 0, 0);
        }
    };
    auto LOADA = [&](int i, float4& a0, float4& a1, float4& a2, float4& a3) {
        const float* ap = xrow + i * KCHUNK;
        a0 = *(const float4*)(ap);
        a1 = *(const float4*)(ap + 4);
        a2 = *(const float4*)(ap + 32);
        a3 = *(const float4*)(ap + 36);
    };
    auto MFMAS = [&](int slot, const half8& a0, const half8& a1) {
        const uint8_t* lb = gring + (size_t)slot * TILEB;
#pragma unroll
        for (int s = 0; s < 2; ++s) {
            half8 ah = s ? a1 : a0;
#pragma unroll
            for (int t = 0; t < 4; ++t) {
                half8 bh = *(const half8*)(lb + boff[t][s]);
                acc[t] = __builtin_amdgcn_mfma_f32_16x16x32_f16(ah, bh, acc[t], 0, 0, 0);
            }
        }
    };

    float4 A0, A1, A2, A3, B0, B1, B2, B3;

    // ---- prologue: stage chunks 0,1,2 (slots 0,1,2); load A(0), A(1) ----
    STAGE(0); STAGE(1); STAGE(2);
    __builtin_amdgcn_sched_barrier(0);
    LOADA(0, A0, A1, A2, A3);
    LOADA(1, B0, B1, B2, B3);
    __builtin_amdgcn_sched_barrier(0);
    asm volatile("s_waitcnt vmcnt(12)" ::: "memory");   // S(0) done; rest in flight
    __builtin_amdgcn_s_barrier();
    __builtin_amdgcn_sched_barrier(0);

    // ---- rounds 0..11 (steady state), unrolled by 2 ----
#pragma unroll 1
    for (int i = 0; i < 12; i += 2) {
        // round i (even, A-set)
        STAGE(i + 3);
        __builtin_amdgcn_sched_barrier(0);
        {
            half8 a0 = cvt8(A0, A1);
            half8 a1 = cvt8(A2, A3);
            LOADA(i + 2, A0, A1, A2, A3);
            MFMAS(i & 3, a0, a1);
        }
        asm volatile("s_waitcnt vmcnt(16) lgkmcnt(0)" ::: "memory"); // S(i+1) done
        __builtin_amdgcn_s_barrier();
        __builtin_amdgcn_sched_barrier(0);

        // round i+1 (odd, B-set)
        STAGE(i + 4);
        __builtin_amdgcn_sched_barrier(0);
        {
            half8 a0 = cvt8(B0, B1);
            half8 a1 = cvt8(B2, B3);
            LOADA(i + 3, B0, B1, B2, B3);
            MFMAS((i + 1) & 3, a0, a1);
        }
        asm volatile("s_waitcnt vmcnt(16) lgkmcnt(0)" ::: "memory"); // S(i+2) done
        __builtin_amdgcn_s_barrier();
        __builtin_amdgcn_sched_barrier(0);
    }

    // ---- round 12 (even): last STAGE (chunk 15), LOADA(14) ----
    STAGE(15);
    __builtin_amdgcn_sched_barrier(0);
    {
        half8 a0 = cvt8(A0, A1);
        half8 a1 = cvt8(A2, A3);
        LOADA(14, A0, A1, A2, A3);
        MFMAS(0, a0, a1);   // 12 & 3
    }
    asm volatile("s_waitcnt vmcnt(16) lgkmcnt(0)" ::: "memory");     // S(13) done
    __builtin_amdgcn_s_barrier();
    __builtin_amdgcn_sched_barrier(0);

    // ---- round 13 (odd): LOADA(15) only ----
    {
        half8 a0 = cvt8(B0, B1);
        half8 a1 = cvt8(B2, B3);
        LOADA(15, B0, B1, B2, B3);
        MFMAS(1, a0, a1);   // 13 & 3
    }
    asm volatile("s_waitcnt vmcnt(14) lgkmcnt(0)" ::: "memory");     // S(14) done
    __builtin_amdgcn_s_barrier();
    __builtin_amdgcn_sched_barrier(0);

    // ---- round 14 (even) ----
    {
        half8 a0 = cvt8(A0, A1);
        half8 a1 = cvt8(A2, A3);
        MFMAS(2, a0, a1);   // 14 & 3
    }
    asm volatile("s_waitcnt vmcnt(8) lgkmcnt(0)" ::: "memory");      // S(15) done
    __builtin_amdgcn_s_barrier();
    __builtin_amdgcn_sched_barrier(0);

    // ---- round 15 (odd) ----
    {
        half8 a0 = cvt8(B0, B1);
        half8 a1 = cvt8(B2, B3);
        MFMAS(3, a0, a1);   // 15 & 3
    }

    // ---- combine K-halves via LDS (overlay on W ring) ----
    __syncthreads();
    {
        float* lgt = (float*)lds + g * LGT_FLOATS;
#pragma unroll
        for (int t = 0; t < 4; ++t)
#pragma unroll
            for (int r = 0; r < 4; ++r)
                lgt[(q * 16 + l4 * 4 + r) * LGT_STRIDE + t * 16 + l15] = acc[t][r];
    }
    __syncthreads();

    // ---------------- entmax-1.5 epilogue ----------------
    // 8 lanes per row, 8 experts per lane; reductions = 3 x shfl_xor {1,2,4}.
    const float* L0 = (const float*)lds;
    const float* L1 = L0 + LGT_FLOATS;
    const int row_local = wave * 8 + (lane >> 3);
    const int eb = (lane & 7) * 8;
    const int base = row_local * LGT_STRIDE + eb;

    float v[8];
    {
        float4 u0 = *(const float4*)(L0 + base);
        float4 u1 = *(const float4*)(L0 + base + 4);
        float4 w0 = *(const float4*)(L1 + base);
        float4 w1 = *(const float4*)(L1 + base + 4);
        float4 c0 = *(const float4*)(bias + eb);
        float4 c1 = *(const float4*)(bias + eb + 4);
        v[0] = u0.x + w0.x + 0.5f * c0.x;
        v[1] = u0.y + w0.y + 0.5f * c0.y;
        v[2] = u0.z + w0.z + 0.5f * c0.z;
        v[3] = u0.w + w0.w + 0.5f * c0.w;
        v[4] = u1.x + w1.x + 0.5f * c1.x;
        v[5] = u1.y + w1.y + 0.5f * c1.y;
        v[6] = u1.z + w1.z + 0.5f * c1.z;
        v[7] = u1.w + w1.w + 0.5f * c1.w;
    }

    float m = v[0];
#pragma unroll
    for (int j = 1; j < 8; ++j) m = fmaxf(m, v[j]);
    m = fmaxf(m, __shfl_xor(m, 1, 64));
    m = fmaxf(m, __shfl_xor(m, 2, 64));
    m = fmaxf(m, __shfl_xor(m, 4, 64));

    float tau_lo = m - 1.0f;
    float tau_hi = m - 0.000244140625f;   // (1/64)^(1/(alpha-1)) = (1/64)^2
    float dm = tau_hi - tau_lo;

    float s0 = 0.f;
#pragma unroll
    for (int j = 0; j < 8; ++j) {
        float d = fmaxf(v[j] - tau_lo, 0.f);
        s0 = fmaf(d, d, s0);
    }
    s0 += __shfl_xor(s0, 1, 64);
    s0 += __shfl_xor(s0, 2, 64);
    s0 += __shfl_xor(s0, 4, 64);
    const float f_lo = s0 - 1.0f;   // fixed for all iterations (as in reference)

    float tau_m = tau_lo, fsum = 1.0f;
#pragma unroll 1
    for (int it = 0; it < 25; ++it) {
        dm *= 0.5f;
        tau_m = tau_lo + dm;
        float s = 0.f;
#pragma unroll
        for (int j = 0; j < 8; ++j) {
            float d = fmaxf(v[j] - tau_m, 0.f);
            s = fmaf(d, d, s);
        }
        s += __shfl_xor(s, 1, 64);
        s += __shfl_xor(s, 2, 64);
        s += __shfl_xor(s, 4, 64);
        if ((s - 1.0f) * f_lo >= 0.0f) tau_lo = tau_m;
        fsum = s;
    }
    // p at last midpoint, renormalized by its own sum (ensure_sum_one)
    float rinv = 1.0f / fsum;
    float4 o0, o1;
    {
        float d;
        d = fmaxf(v[0] - tau_m, 0.f); o0.x = d * d * rinv;
        d = fmaxf(v[1] - tau_m, 0.f); o0.y = d * d * rinv;
        d = fmaxf(v[2] - tau_m, 0.f); o0.z = d * d * rinv;
        d = fmaxf(v[3] - tau_m, 0.f); o0.w = d * d * rinv;
        d = fmaxf(v[4] - tau_m, 0.f); o1.x = d * d * rinv;
        d = fmaxf(v[5] - tau_m, 0.f); o1.y = d * d * rinv;
        d = fmaxf(v[6] - tau_m, 0.f); o1.z = d * d * rinv;
        d = fmaxf(v[7] - tau_m, 0.f); o1.w = d * d * rinv;
    }
    float* op = out + (size_t)(rowbase + row_local) * N_EXP + eb;
    *(float4*)(op)     = o0;
    *(float4*)(op + 4) = o1;
}

// ---------------------------------------------------------------------------
extern "C" void kernel_launch(void* const* d_in, const int* in_sizes, int n_in,
                              void* d_out, int out_size, void* d_ws, size_t ws_size,
                              hipStream_t stream) {
    (void)n_in; (void)out_size; (void)ws_size;
    const float* x  = (const float*)d_in[0];   // [T, 2048]
    const float* W  = (const float*)d_in[1];   // [64, 2048]
    const float* b  = (const float*)d_in[2];   // [64]
    float* out      = (float*)d_out;           // [T, 64]
    uint8_t* wsimg  = (uint8_t*)d_ws;          // 256 KB W fp16 image

    const int T = in_sizes[0] / N_EMBED;       // 32768

    convert_w_kernel<<<dim3(64), dim3(256), 0, stream>>>(W, wsimg);
    router_kernel<<<dim3(T / 64), dim3(512), 0, stream>>>(x, wsimg, b, out);
}